// Round 6
// baseline (1273.684 us; speedup 1.0000x reference)
//
#include <hip/hip_runtime.h>

typedef unsigned int uint32;

// Problem constants
#define DD    2048
#define LP1   513
#define TT    65
#define FOURD 8192

// ---------- helpers ----------
__device__ __forceinline__ float frcp(float x) { return __builtin_amdgcn_rcpf(x); }
__device__ __forceinline__ float sigm(float x) {
    return frcp(1.f + exp2f(-1.4426950408889634f * x));
}
__device__ __forceinline__ float tanh_fast(float x) {
    float e = exp2f(2.8853900817779268f * x);    // e^(2x)
    return fmaf(-2.f, frcp(1.f + e), 1.f);       // 1 - 2/(1+e^(2x))
}

// ---------- K0: xg[t][r] = b_ih[r]+b_hh[r]+W_ih[r,:]@x_t ----------
__global__ __launch_bounds__(256) void xg_kernel(
    const float* __restrict__ W_ih, const float* __restrict__ b_ih,
    const float* __restrict__ b_hh, const float* __restrict__ seq,
    const int* __restrict__ pos, float* __restrict__ xg)
{
    int t = blockIdx.y;
    int r = blockIdx.x * 256 + threadIdx.x;   // [0, 8192)
    float x0, x1, x2;
    if (t == 0) { x0 = 0.f; x1 = 0.f; x2 = 1.f; }   // special symbol
    else {
        int p = pos[t - 1];
        x0 = seq[p * 3 + 0]; x1 = seq[p * 3 + 1]; x2 = seq[p * 3 + 2];
    }
    float acc = b_ih[r] + b_hh[r];
    acc = fmaf(W_ih[r * 3 + 0], x0, acc);
    acc = fmaf(W_ih[r * 3 + 1], x1, acc);
    acc = fmaf(W_ih[r * 3 + 2], x2, acc);
    xg[(size_t)t * FOURD + r] = acc;
}

// ---------- K1/K3: C[M,N] = A[M,K] @ B[N,K]^T + bias (all fp32) ----------
__global__ __launch_bounds__(256) void gemm_nt_kernel(
    const float* __restrict__ A, const float* __restrict__ B,
    const float* __restrict__ bias, float* __restrict__ C,
    int M, int N, int K)
{
    __shared__ float As[16][68];   // k-major, padded
    __shared__ float Bs[16][68];
    int tid = threadIdx.x;
    int tx = tid & 15, ty = tid >> 4;
    int m0 = blockIdx.y * 64, n0 = blockIdx.x * 64;
    int lr = tid >> 2;            // 0..63 row within tile
    int lk = (tid & 3) << 2;      // k offset 0,4,8,12
    float acc[4][4] = {};

    for (int k0 = 0; k0 < K; k0 += 16) {
        float4 av4 = {0.f, 0.f, 0.f, 0.f};
        int m = m0 + lr;
        if (m < M) av4 = *(const float4*)(A + (size_t)m * K + k0 + lk);
        float4 bv4 = *(const float4*)(B + (size_t)(n0 + lr) * K + k0 + lk); // N%64==0

        __syncthreads();   // previous iteration's reads complete
        As[lk + 0][lr] = av4.x; As[lk + 1][lr] = av4.y;
        As[lk + 2][lr] = av4.z; As[lk + 3][lr] = av4.w;
        Bs[lk + 0][lr] = bv4.x; Bs[lk + 1][lr] = bv4.y;
        Bs[lk + 2][lr] = bv4.z; Bs[lk + 3][lr] = bv4.w;
        __syncthreads();

        #pragma unroll
        for (int kk = 0; kk < 16; kk++) {
            float4 av = *(const float4*)&As[kk][ty << 2];
            float4 bv = *(const float4*)&Bs[kk][tx << 2];
            acc[0][0] = fmaf(av.x, bv.x, acc[0][0]); acc[0][1] = fmaf(av.x, bv.y, acc[0][1]);
            acc[0][2] = fmaf(av.x, bv.z, acc[0][2]); acc[0][3] = fmaf(av.x, bv.w, acc[0][3]);
            acc[1][0] = fmaf(av.y, bv.x, acc[1][0]); acc[1][1] = fmaf(av.y, bv.y, acc[1][1]);
            acc[1][2] = fmaf(av.y, bv.z, acc[1][2]); acc[1][3] = fmaf(av.y, bv.w, acc[1][3]);
            acc[2][0] = fmaf(av.z, bv.x, acc[2][0]); acc[2][1] = fmaf(av.z, bv.y, acc[2][1]);
            acc[2][2] = fmaf(av.z, bv.z, acc[2][2]); acc[2][3] = fmaf(av.z, bv.w, acc[2][3]);
            acc[3][0] = fmaf(av.w, bv.x, acc[3][0]); acc[3][1] = fmaf(av.w, bv.y, acc[3][1]);
            acc[3][2] = fmaf(av.w, bv.z, acc[3][2]); acc[3][3] = fmaf(av.w, bv.w, acc[3][3]);
        }
    }
    #pragma unroll
    for (int i = 0; i < 4; i++) {
        int m = m0 + (ty << 2) + i;
        if (m < M) {
            #pragma unroll
            for (int j = 0; j < 4; j++) {
                int n = n0 + (tx << 2) + j;
                C[(size_t)m * N + n] = acc[i][j] + bias[n];
            }
        }
    }
}

// ---------- K2 (x65): ONE LSTM step. No grid sync anywhere — launched
// sequentially; kernel boundaries guarantee cross-XCD visibility of H/c.
// 512 blocks x 256 threads; wave w of block b owns dim d = 4b+w and
// computes 4 gate dot-products (W rows g*2048+d) with float4 loads.
__global__ __launch_bounds__(256) void lstm_step_kernel(
    const float* __restrict__ Whh, const float* __restrict__ init_h,
    const float* __restrict__ xg, float* __restrict__ Hws,
    float* __restrict__ c_buf, int t)
{
    __shared__ float4 h_s4[512];   // 8 KB: h_{t-1}
    int tid = threadIdx.x;
    int b = blockIdx.x;
    int wave = tid >> 6, lane = tid & 63;
    int d = b * 4 + wave;

    {   // stage h_{t-1} (both sources 16B-aligned)
        const float4* src = (t == 0) ? (const float4*)init_h
                                     : (const float4*)(Hws + (size_t)(t - 1) * DD);
        h_s4[tid] = src[tid];
        h_s4[tid + 256] = src[tid + 256];
    }
    __syncthreads();

    const float4* Wq = (const float4*)Whh;   // row r: Wq[r*512 + j], j<512
    float s0 = 0.f, s1 = 0.f, s2 = 0.f, s3 = 0.f;
    #pragma unroll
    for (int i = 0; i < 8; i++) {
        int p = i * 64 + lane;               // 0..511
        float4 h = h_s4[p];
        float4 w0 = Wq[(size_t)(0 * DD + d) * 512 + p];
        float4 w1 = Wq[(size_t)(1 * DD + d) * 512 + p];
        float4 w2 = Wq[(size_t)(2 * DD + d) * 512 + p];
        float4 w3 = Wq[(size_t)(3 * DD + d) * 512 + p];
        s0 = fmaf(w0.x, h.x, s0); s0 = fmaf(w0.y, h.y, s0);
        s0 = fmaf(w0.z, h.z, s0); s0 = fmaf(w0.w, h.w, s0);
        s1 = fmaf(w1.x, h.x, s1); s1 = fmaf(w1.y, h.y, s1);
        s1 = fmaf(w1.z, h.z, s1); s1 = fmaf(w1.w, h.w, s1);
        s2 = fmaf(w2.x, h.x, s2); s2 = fmaf(w2.y, h.y, s2);
        s2 = fmaf(w2.z, h.z, s2); s2 = fmaf(w2.w, h.w, s2);
        s3 = fmaf(w3.x, h.x, s3); s3 = fmaf(w3.y, h.y, s3);
        s3 = fmaf(w3.z, h.z, s3); s3 = fmaf(w3.w, h.w, s3);
    }
    #pragma unroll
    for (int off = 1; off < 64; off <<= 1) {
        s0 += __shfl_xor(s0, off); s1 += __shfl_xor(s1, off);
        s2 += __shfl_xor(s2, off); s3 += __shfl_xor(s3, off);
    }
    const float* xgt = xg + (size_t)t * FOURD;
    s0 += xgt[d]; s1 += xgt[DD + d]; s2 += xgt[2 * DD + d]; s3 += xgt[3 * DD + d];

    float cprev = (t == 0) ? 0.f : c_buf[d];
    float ig = sigm(s0), fg = sigm(s1), gg = tanh_fast(s2), og = sigm(s3);
    float c = fmaf(fg, cprev, ig * gg);
    float hh = og * tanh_fast(c);
    if (lane == 0) {
        c_buf[d] = c;
        Hws[(size_t)t * DD + d] = hh;
    }
}

// ---------- K2b: copy Hws -> d_out hidden slice ----------
__global__ __launch_bounds__(256) void copyh_kernel(
    const float* __restrict__ Hws, float* __restrict__ outH)
{
    int i = blockIdx.x * 256 + threadIdx.x;   // grid covers 65*2048 exactly
    outH[i] = Hws[i];
}

// ---------- K4: logits[t][l] = v_b + sum_v vw[v]*tanh(enc_proj[l][v]+Dm[t][v]) ----------
__global__ __launch_bounds__(256) void ptr_kernel(
    const float* __restrict__ enc_proj, const float* __restrict__ Dm,
    const float* __restrict__ vw, const float* __restrict__ vb,
    float* __restrict__ outL)
{
    __shared__ float Dm_s[6][DD];    // 48 KB
    __shared__ float vw_s[DD];       // 8 KB
    int tid = threadIdx.x;
    int t0 = blockIdx.y * 6;
    int l0 = blockIdx.x * 64;

    for (int tt = 0; tt < 6; tt++) {
        int t = t0 + tt;
        float4* dst = (float4*)(Dm_s[tt]);
        if (t < TT) {
            const float4* src = (const float4*)(Dm + (size_t)t * DD);
            dst[tid] = src[tid]; dst[tid + 256] = src[tid + 256];
        } else {
            float4 z = {0.f, 0.f, 0.f, 0.f};
            dst[tid] = z; dst[tid + 256] = z;
        }
    }
    {   // vw: 2048 floats = 512 float4; 256 threads x 2
        float4* dv = (float4*)vw_s;
        const float4* sv = (const float4*)vw;
        dv[tid] = sv[tid];
        dv[tid + 256] = sv[tid + 256];
    }
    __syncthreads();

    int wave = tid >> 6, lane = tid & 63;
    float vbf = vb[0];

    for (int lo = wave; lo < 64; lo += 4) {
        int l = l0 + lo;
        if (l >= LP1) break;
        const float* ep = enc_proj + (size_t)l * DD;
        float acc[6] = {0.f, 0.f, 0.f, 0.f, 0.f, 0.f};
        #pragma unroll 4
        for (int i2 = 0; i2 < 32; i2++) {
            int v = lane + (i2 << 6);
            float e = ep[v];
            #pragma unroll
            for (int tt = 0; tt < 6; tt++) {
                acc[tt] = fmaf(vw_s[v], tanh_fast(e + Dm_s[tt][v]), acc[tt]);
            }
        }
        #pragma unroll
        for (int off = 1; off < 64; off <<= 1) {
            #pragma unroll
            for (int tt = 0; tt < 6; tt++) acc[tt] += __shfl_xor(acc[tt], off);
        }
        if (lane == 0) {
            #pragma unroll
            for (int tt = 0; tt < 6; tt++) {
                int t = t0 + tt;
                if (t < TT) outL[(size_t)t * LP1 + l] = acc[tt] + vbf;
            }
        }
    }
}

// ---------- K5: losses[t] = logsumexp(logits[t]) - logits[t][tgt] ----------
__global__ __launch_bounds__(256) void loss_kernel(
    const float* __restrict__ LG, const int* __restrict__ pos,
    float* __restrict__ outLoss)
{
    int t = blockIdx.x, tid = threadIdx.x;
    __shared__ float red[256];
    const float* row = LG + (size_t)t * LP1;

    float m = -3.4e38f;
    for (int i = tid; i < LP1; i += 256) m = fmaxf(m, row[i]);
    red[tid] = m; __syncthreads();
    for (int s = 128; s > 0; s >>= 1) {
        if (tid < s) red[tid] = fmaxf(red[tid], red[tid + s]);
        __syncthreads();
    }
    float mx = red[0]; __syncthreads();

    float sum = 0.f;
    for (int i = tid; i < LP1; i += 256)
        sum += exp2f((row[i] - mx) * 1.4426950408889634f);
    red[tid] = sum; __syncthreads();
    for (int s = 128; s > 0; s >>= 1) {
        if (tid < s) red[tid] += red[tid + s];
        __syncthreads();
    }
    if (tid == 0) {
        int tgt = (t < TT - 1) ? pos[t] : (LP1 - 1);
        float lse = mx + 0.6931471805599453f * log2f(red[0]);
        outLoss[t] = lse - row[tgt];
    }
}

// ---------- host ----------
extern "C" void kernel_launch(void* const* d_in, const int* in_sizes, int n_in,
                              void* d_out, int out_size, void* d_ws, size_t ws_size,
                              hipStream_t stream) {
    const float* init_h = (const float*)d_in[0];
    const float* enc    = (const float*)d_in[1];
    const float* seq    = (const float*)d_in[2];
    const int*   pos    = (const int*)d_in[3];
    const float* W_ih   = (const float*)d_in[4];
    const float* W_hh   = (const float*)d_in[5];
    const float* b_ih   = (const float*)d_in[6];
    const float* b_hh   = (const float*)d_in[7];
    const float* We_w   = (const float*)d_in[8];
    const float* We_b   = (const float*)d_in[9];
    const float* Wd_w   = (const float*)d_in[10];
    const float* Wd_b   = (const float*)d_in[11];
    const float* v_w    = (const float*)d_in[12];
    const float* v_b    = (const float*)d_in[13];
    float* out = (float*)d_out;

    // out layout: logits[65*513] | hidden[65*2048] | losses[65]  (fp32)
    float* outL    = out;
    float* outH    = out + (size_t)TT * LP1;
    float* outLoss = outH + (size_t)TT * DD;

    // ws layout (fp32), all 16B-aligned slices:
    float* ws = (float*)d_ws;
    float* Hws      = ws;                          // 65*2048   = 133120
    float* c_buf    = Hws + (size_t)TT * DD;       // 2048
    float* enc_proj = c_buf + DD;                  // 513*2048  = 1050624
    float* xg       = enc_proj + (size_t)LP1 * DD; // 65*8192   = 532480
    float* Dm       = xg + (size_t)TT * FOURD;     // 65*2048   (total ~7 MB)

    // K0: teacher-forced input-gate biases
    xg_kernel<<<dim3(32, TT), 256, 0, stream>>>(W_ih, b_ih, b_hh, seq, pos, xg);

    // K1: enc_proj = enc @ We^T + We_b   [513 x 2048]
    gemm_nt_kernel<<<dim3(32, 9), 256, 0, stream>>>(enc, We_w, We_b, enc_proj,
                                                    LP1, DD, DD);

    // K2: LSTM recurrence as 65 sequential step launches (no grid sync;
    // kernel boundaries provide cross-XCD visibility of Hws/c_buf)
    for (int t = 0; t < TT; t++) {
        lstm_step_kernel<<<dim3(512), 256, 0, stream>>>(W_hh, init_h, xg,
                                                        Hws, c_buf, t);
    }

    // K2b: hidden states to output
    copyh_kernel<<<dim3((TT * DD) / 256), 256, 0, stream>>>(Hws, outH);

    // K3: Dm = Hws @ Wd^T + Wd_b   [65 x 2048]
    gemm_nt_kernel<<<dim3(32, 2), 256, 0, stream>>>(Hws, Wd_w, Wd_b, Dm,
                                                    TT, DD, DD);

    // K4: pointer logits
    ptr_kernel<<<dim3(9, 11), 256, 0, stream>>>(enc_proj, Dm, v_w, v_b, outL);

    // K5: losses
    loss_kernel<<<TT, 256, 0, stream>>>(outL, pos, outLoss);
}

// Round 7
// 779.223 us; speedup vs baseline: 1.6346x; 1.6346x over previous
//
#include <hip/hip_runtime.h>

typedef unsigned int uint32;
typedef unsigned short u16;

// Problem constants
#define DD    2048
#define LP1   513
#define TT    65
#define FOURD 8192

typedef __attribute__((ext_vector_type(8))) short short8;   // 8 bf16 (4 VGPRs)
typedef __attribute__((ext_vector_type(4))) float f32x4;

// ---------- helpers ----------
__device__ __forceinline__ float frcp(float x) { return __builtin_amdgcn_rcpf(x); }
__device__ __forceinline__ float sigm(float x) {
    return frcp(1.f + exp2f(-1.4426950408889634f * x));
}
__device__ __forceinline__ float tanh_fast(float x) {
    float e = exp2f(2.8853900817779268f * x);    // e^(2x)
    return fmaf(-2.f, frcp(1.f + e), 1.f);       // 1 - 2/(1+e^(2x))
}
__device__ __forceinline__ float bflo(uint32 w) {
    union { uint32 i; float f; } c; c.i = w << 16; return c.f;
}
__device__ __forceinline__ float bfhi(uint32 w) {
    union { uint32 i; float f; } c; c.i = w & 0xffff0000u; return c.f;
}
__device__ __forceinline__ uint32 f2bf(float f) {   // RNE, returns low 16
    union { float f; uint32 i; } c; c.f = f;
    return (c.i + 0x7fffu + ((c.i >> 16) & 1u)) >> 16;
}
__device__ __forceinline__ uint32 pack2(float a, float b) {
    return f2bf(a) | (f2bf(b) << 16);
}

// ---------- K-1: convert W_hh fp32 -> bf16 (once per call) ----------
__global__ __launch_bounds__(256) void conv_whh_kernel(
    const float* __restrict__ src, u16* __restrict__ dst)
{
    size_t i = ((size_t)blockIdx.x * 256 + threadIdx.x) * 8;   // grid covers 4*2048*2048
    float4 a = *(const float4*)(src + i);
    float4 b = *(const float4*)(src + i + 4);
    uint4 o;
    o.x = pack2(a.x, a.y); o.y = pack2(a.z, a.w);
    o.z = pack2(b.x, b.y); o.w = pack2(b.z, b.w);
    *(uint4*)(dst + i) = o;
}

// ---------- K0: xg[t][r] = b_ih[r]+b_hh[r]+W_ih[r,:]@x_t ----------
__global__ __launch_bounds__(256) void xg_kernel(
    const float* __restrict__ W_ih, const float* __restrict__ b_ih,
    const float* __restrict__ b_hh, const float* __restrict__ seq,
    const int* __restrict__ pos, float* __restrict__ xg)
{
    int t = blockIdx.y;
    int r = blockIdx.x * 256 + threadIdx.x;   // [0, 8192)
    float x0, x1, x2;
    if (t == 0) { x0 = 0.f; x1 = 0.f; x2 = 1.f; }   // special symbol
    else {
        int p = pos[t - 1];
        x0 = seq[p * 3 + 0]; x1 = seq[p * 3 + 1]; x2 = seq[p * 3 + 2];
    }
    float acc = b_ih[r] + b_hh[r];
    acc = fmaf(W_ih[r * 3 + 0], x0, acc);
    acc = fmaf(W_ih[r * 3 + 1], x1, acc);
    acc = fmaf(W_ih[r * 3 + 2], x2, acc);
    xg[(size_t)t * FOURD + r] = acc;
}

// ---------- K1/K3: MFMA GEMM  C[M,N] = A[M,K]@B[N,K]^T + bias ----------
// A,B fp32 in global, converted to bf16 at LDS-stage time. N%128==0, K%32==0.
// 256 threads = 4 waves in 2x2; block tile 128x128; wave tile 64x64 =
// 4x4 of 16x16x32 mfma. LDS row stride 40 (power-of-2 break).
#define LSTR 40
__global__ __launch_bounds__(256) void mfma_gemm_kernel(
    const float* __restrict__ A, const float* __restrict__ B,
    const float* __restrict__ bias, float* __restrict__ C,
    int M, int N, int K)
{
    __shared__ u16 As[128 * LSTR];
    __shared__ u16 Bs[128 * LSTR];
    int tid = threadIdx.x;
    int wave = tid >> 6, lane = tid & 63;
    int m0 = blockIdx.y * 128, n0 = blockIdx.x * 128;
    int wm = (wave >> 1) * 64, wn = (wave & 1) * 64;
    int srow = tid >> 1, sseg = (tid & 1) * 16;   // stage: row 0..127, seg 0/16

    f32x4 acc[4][4] = {};

    for (int k0 = 0; k0 < K; k0 += 32) {
        // global fp32 loads (16 elems each of A and B)
        float4 a0 = {0,0,0,0}, a1 = a0, a2 = a0, a3 = a0;
        int am = m0 + srow;
        if (am < M) {
            const float4* ap = (const float4*)(A + (size_t)am * K + k0 + sseg);
            a0 = ap[0]; a1 = ap[1]; a2 = ap[2]; a3 = ap[3];
        }
        const float4* bp = (const float4*)(B + (size_t)(n0 + srow) * K + k0 + sseg);
        float4 b0 = bp[0], b1 = bp[1], b2 = bp[2], b3 = bp[3];

        __syncthreads();   // previous tile's fragment reads done
        {
            uint4 oa, ob;
            oa.x = pack2(a0.x, a0.y); oa.y = pack2(a0.z, a0.w);
            oa.z = pack2(a1.x, a1.y); oa.w = pack2(a1.z, a1.w);
            uint4* ad = (uint4*)(As + srow * LSTR + sseg);
            ad[0] = oa;
            oa.x = pack2(a2.x, a2.y); oa.y = pack2(a2.z, a2.w);
            oa.z = pack2(a3.x, a3.y); oa.w = pack2(a3.z, a3.w);
            ad[1] = oa;
            ob.x = pack2(b0.x, b0.y); ob.y = pack2(b0.z, b0.w);
            ob.z = pack2(b1.x, b1.y); ob.w = pack2(b1.z, b1.w);
            uint4* bd = (uint4*)(Bs + srow * LSTR + sseg);
            bd[0] = ob;
            ob.x = pack2(b2.x, b2.y); ob.y = pack2(b2.z, b2.w);
            ob.z = pack2(b3.x, b3.y); ob.w = pack2(b3.z, b3.w);
            bd[1] = ob;
        }
        __syncthreads();

        // fragments: lane holds 8 consecutive k at quad*8; row = tile + (lane&15)
        int fr = lane & 15, fq = (lane >> 4) * 8;
        short8 af[4], bf[4];
        #pragma unroll
        for (int i = 0; i < 4; i++)
            af[i] = *(const short8*)(As + (wm + i * 16 + fr) * LSTR + fq);
        #pragma unroll
        for (int j = 0; j < 4; j++)
            bf[j] = *(const short8*)(Bs + (wn + j * 16 + fr) * LSTR + fq);
        #pragma unroll
        for (int i = 0; i < 4; i++)
            #pragma unroll
            for (int j = 0; j < 4; j++)
                acc[i][j] = __builtin_amdgcn_mfma_f32_16x16x32_bf16(
                    af[i], bf[j], acc[i][j], 0, 0, 0);
    }

    // epilogue: C/D layout col=lane&15, row=(lane>>4)*4+reg  [m89-verified]
    int cn = lane & 15, cr = (lane >> 4) * 4;
    #pragma unroll
    for (int i = 0; i < 4; i++) {
        #pragma unroll
        for (int r = 0; r < 4; r++) {
            int m = m0 + wm + i * 16 + cr + r;
            if (m < M) {
                #pragma unroll
                for (int j = 0; j < 4; j++) {
                    int n = n0 + wn + j * 16 + cn;
                    C[(size_t)m * N + n] = acc[i][j][r] + bias[n];
                }
            }
        }
    }
}

// ---------- K2 (x65): one LSTM step, W_hh in bf16 ----------
// 512 blocks x 256 threads; wave w of block b owns dim d = 4b+w.
__global__ __launch_bounds__(256) void lstm_step_bf16_kernel(
    const u16* __restrict__ Wb, const float* __restrict__ init_h,
    const float* __restrict__ xg, float* __restrict__ Hws,
    float* __restrict__ c_buf, int t)
{
    __shared__ float4 h_s4[512];   // 8 KB: h_{t-1}
    int tid = threadIdx.x;
    int b = blockIdx.x;
    int wave = tid >> 6, lane = tid & 63;
    int d = b * 4 + wave;

    {
        const float4* src = (t == 0) ? (const float4*)init_h
                                     : (const float4*)(Hws + (size_t)(t - 1) * DD);
        h_s4[tid] = src[tid];
        h_s4[tid + 256] = src[tid + 256];
    }
    __syncthreads();

    const uint4* Wq = (const uint4*)Wb;   // row r: 256 uint4 (2048 bf16)
    float s0 = 0.f, s1 = 0.f, s2 = 0.f, s3 = 0.f;
    #pragma unroll
    for (int i = 0; i < 4; i++) {
        int p = i * 64 + lane;            // uint4 index 0..255 → k = 8p..8p+7
        float4 ha = h_s4[2 * p], hb = h_s4[2 * p + 1];
        uint4 w0 = Wq[(size_t)(0 * DD + d) * 256 + p];
        uint4 w1 = Wq[(size_t)(1 * DD + d) * 256 + p];
        uint4 w2 = Wq[(size_t)(2 * DD + d) * 256 + p];
        uint4 w3 = Wq[(size_t)(3 * DD + d) * 256 + p];
        s0 = fmaf(bflo(w0.x), ha.x, s0); s0 = fmaf(bfhi(w0.x), ha.y, s0);
        s0 = fmaf(bflo(w0.y), ha.z, s0); s0 = fmaf(bfhi(w0.y), ha.w, s0);
        s0 = fmaf(bflo(w0.z), hb.x, s0); s0 = fmaf(bfhi(w0.z), hb.y, s0);
        s0 = fmaf(bflo(w0.w), hb.z, s0); s0 = fmaf(bfhi(w0.w), hb.w, s0);
        s1 = fmaf(bflo(w1.x), ha.x, s1); s1 = fmaf(bfhi(w1.x), ha.y, s1);
        s1 = fmaf(bflo(w1.y), ha.z, s1); s1 = fmaf(bfhi(w1.y), ha.w, s1);
        s1 = fmaf(bflo(w1.z), hb.x, s1); s1 = fmaf(bfhi(w1.z), hb.y, s1);
        s1 = fmaf(bflo(w1.w), hb.z, s1); s1 = fmaf(bfhi(w1.w), hb.w, s1);
        s2 = fmaf(bflo(w2.x), ha.x, s2); s2 = fmaf(bfhi(w2.x), ha.y, s2);
        s2 = fmaf(bflo(w2.y), ha.z, s2); s2 = fmaf(bfhi(w2.y), ha.w, s2);
        s2 = fmaf(bflo(w2.z), hb.x, s2); s2 = fmaf(bfhi(w2.z), hb.y, s2);
        s2 = fmaf(bflo(w2.w), hb.z, s2); s2 = fmaf(bfhi(w2.w), hb.w, s2);
        s3 = fmaf(bflo(w3.x), ha.x, s3); s3 = fmaf(bfhi(w3.x), ha.y, s3);
        s3 = fmaf(bflo(w3.y), ha.z, s3); s3 = fmaf(bfhi(w3.y), ha.w, s3);
        s3 = fmaf(bflo(w3.z), hb.x, s3); s3 = fmaf(bfhi(w3.z), hb.y, s3);
        s3 = fmaf(bflo(w3.w), hb.z, s3); s3 = fmaf(bfhi(w3.w), hb.w, s3);
    }
    #pragma unroll
    for (int off = 1; off < 64; off <<= 1) {
        s0 += __shfl_xor(s0, off); s1 += __shfl_xor(s1, off);
        s2 += __shfl_xor(s2, off); s3 += __shfl_xor(s3, off);
    }
    const float* xgt = xg + (size_t)t * FOURD;
    s0 += xgt[d]; s1 += xgt[DD + d]; s2 += xgt[2 * DD + d]; s3 += xgt[3 * DD + d];

    float cprev = (t == 0) ? 0.f : c_buf[d];
    float ig = sigm(s0), fg = sigm(s1), gg = tanh_fast(s2), og = sigm(s3);
    float c = fmaf(fg, cprev, ig * gg);
    float hh = og * tanh_fast(c);
    if (lane == 0) {
        c_buf[d] = c;
        Hws[(size_t)t * DD + d] = hh;
    }
}

// ---------- K2-fallback: fp32 step (used if ws too small for bf16 W) ----------
__global__ __launch_bounds__(256) void lstm_step_f32_kernel(
    const float* __restrict__ Whh, const float* __restrict__ init_h,
    const float* __restrict__ xg, float* __restrict__ Hws,
    float* __restrict__ c_buf, int t)
{
    __shared__ float4 h_s4[512];
    int tid = threadIdx.x;
    int b = blockIdx.x;
    int wave = tid >> 6, lane = tid & 63;
    int d = b * 4 + wave;
    {
        const float4* src = (t == 0) ? (const float4*)init_h
                                     : (const float4*)(Hws + (size_t)(t - 1) * DD);
        h_s4[tid] = src[tid];
        h_s4[tid + 256] = src[tid + 256];
    }
    __syncthreads();
    const float4* Wq = (const float4*)Whh;
    float s0 = 0.f, s1 = 0.f, s2 = 0.f, s3 = 0.f;
    #pragma unroll
    for (int i = 0; i < 8; i++) {
        int p = i * 64 + lane;
        float4 h = h_s4[p];
        float4 w0 = Wq[(size_t)(0 * DD + d) * 512 + p];
        float4 w1 = Wq[(size_t)(1 * DD + d) * 512 + p];
        float4 w2 = Wq[(size_t)(2 * DD + d) * 512 + p];
        float4 w3 = Wq[(size_t)(3 * DD + d) * 512 + p];
        s0 = fmaf(w0.x, h.x, s0); s0 = fmaf(w0.y, h.y, s0);
        s0 = fmaf(w0.z, h.z, s0); s0 = fmaf(w0.w, h.w, s0);
        s1 = fmaf(w1.x, h.x, s1); s1 = fmaf(w1.y, h.y, s1);
        s1 = fmaf(w1.z, h.z, s1); s1 = fmaf(w1.w, h.w, s1);
        s2 = fmaf(w2.x, h.x, s2); s2 = fmaf(w2.y, h.y, s2);
        s2 = fmaf(w2.z, h.z, s2); s2 = fmaf(w2.w, h.w, s2);
        s3 = fmaf(w3.x, h.x, s3); s3 = fmaf(w3.y, h.y, s3);
        s3 = fmaf(w3.z, h.z, s3); s3 = fmaf(w3.w, h.w, s3);
    }
    #pragma unroll
    for (int off = 1; off < 64; off <<= 1) {
        s0 += __shfl_xor(s0, off); s1 += __shfl_xor(s1, off);
        s2 += __shfl_xor(s2, off); s3 += __shfl_xor(s3, off);
    }
    const float* xgt = xg + (size_t)t * FOURD;
    s0 += xgt[d]; s1 += xgt[DD + d]; s2 += xgt[2 * DD + d]; s3 += xgt[3 * DD + d];
    float cprev = (t == 0) ? 0.f : c_buf[d];
    float ig = sigm(s0), fg = sigm(s1), gg = tanh_fast(s2), og = sigm(s3);
    float c = fmaf(fg, cprev, ig * gg);
    float hh = og * tanh_fast(c);
    if (lane == 0) {
        c_buf[d] = c;
        Hws[(size_t)t * DD + d] = hh;
    }
}

// ---------- K2b: copy Hws -> d_out hidden slice ----------
__global__ __launch_bounds__(256) void copyh_kernel(
    const float* __restrict__ Hws, float* __restrict__ outH)
{
    int i = blockIdx.x * 256 + threadIdx.x;
    outH[i] = Hws[i];
}

// ---------- K4: logits[t][l] = v_b + sum_v vw[v]*tanh(enc_proj[l][v]+Dm[t][v]) ----------
__global__ __launch_bounds__(256) void ptr_kernel(
    const float* __restrict__ enc_proj, const float* __restrict__ Dm,
    const float* __restrict__ vw, const float* __restrict__ vb,
    float* __restrict__ outL)
{
    __shared__ float Dm_s[6][DD];    // 48 KB
    __shared__ float vw_s[DD];       // 8 KB
    int tid = threadIdx.x;
    int t0 = blockIdx.y * 6;
    int l0 = blockIdx.x * 64;

    for (int tt = 0; tt < 6; tt++) {
        int t = t0 + tt;
        float4* dst = (float4*)(Dm_s[tt]);
        if (t < TT) {
            const float4* src = (const float4*)(Dm + (size_t)t * DD);
            dst[tid] = src[tid]; dst[tid + 256] = src[tid + 256];
        } else {
            float4 z = {0.f, 0.f, 0.f, 0.f};
            dst[tid] = z; dst[tid + 256] = z;
        }
    }
    {
        float4* dv = (float4*)vw_s;
        const float4* sv = (const float4*)vw;
        dv[tid] = sv[tid];
        dv[tid + 256] = sv[tid + 256];
    }
    __syncthreads();

    int wave = tid >> 6, lane = tid & 63;
    float vbf = vb[0];

    for (int lo = wave; lo < 64; lo += 4) {
        int l = l0 + lo;
        if (l >= LP1) break;
        const float* ep = enc_proj + (size_t)l * DD;
        float acc[6] = {0.f, 0.f, 0.f, 0.f, 0.f, 0.f};
        #pragma unroll 4
        for (int i2 = 0; i2 < 32; i2++) {
            int v = lane + (i2 << 6);
            float e = ep[v];
            #pragma unroll
            for (int tt = 0; tt < 6; tt++) {
                acc[tt] = fmaf(vw_s[v], tanh_fast(e + Dm_s[tt][v]), acc[tt]);
            }
        }
        #pragma unroll
        for (int off = 1; off < 64; off <<= 1) {
            #pragma unroll
            for (int tt = 0; tt < 6; tt++) acc[tt] += __shfl_xor(acc[tt], off);
        }
        if (lane == 0) {
            #pragma unroll
            for (int tt = 0; tt < 6; tt++) {
                int t = t0 + tt;
                if (t < TT) outL[(size_t)t * LP1 + l] = acc[tt] + vbf;
            }
        }
    }
}

// ---------- K5: losses[t] = logsumexp(logits[t]) - logits[t][tgt] ----------
__global__ __launch_bounds__(256) void loss_kernel(
    const float* __restrict__ LG, const int* __restrict__ pos,
    float* __restrict__ outLoss)
{
    int t = blockIdx.x, tid = threadIdx.x;
    __shared__ float red[256];
    const float* row = LG + (size_t)t * LP1;

    float m = -3.4e38f;
    for (int i = tid; i < LP1; i += 256) m = fmaxf(m, row[i]);
    red[tid] = m; __syncthreads();
    for (int s = 128; s > 0; s >>= 1) {
        if (tid < s) red[tid] = fmaxf(red[tid], red[tid + s]);
        __syncthreads();
    }
    float mx = red[0]; __syncthreads();

    float sum = 0.f;
    for (int i = tid; i < LP1; i += 256)
        sum += exp2f((row[i] - mx) * 1.4426950408889634f);
    red[tid] = sum; __syncthreads();
    for (int s = 128; s > 0; s >>= 1) {
        if (tid < s) red[tid] += red[tid + s];
        __syncthreads();
    }
    if (tid == 0) {
        int tgt = (t < TT - 1) ? pos[t] : (LP1 - 1);
        float lse = mx + 0.6931471805599453f * log2f(red[0]);
        outLoss[t] = lse - row[tgt];
    }
}

// ---------- host ----------
extern "C" void kernel_launch(void* const* d_in, const int* in_sizes, int n_in,
                              void* d_out, int out_size, void* d_ws, size_t ws_size,
                              hipStream_t stream) {
    const float* init_h = (const float*)d_in[0];
    const float* enc    = (const float*)d_in[1];
    const float* seq    = (const float*)d_in[2];
    const int*   pos    = (const int*)d_in[3];
    const float* W_ih   = (const float*)d_in[4];
    const float* W_hh   = (const float*)d_in[5];
    const float* b_ih   = (const float*)d_in[6];
    const float* b_hh   = (const float*)d_in[7];
    const float* We_w   = (const float*)d_in[8];
    const float* We_b   = (const float*)d_in[9];
    const float* Wd_w   = (const float*)d_in[10];
    const float* Wd_b   = (const float*)d_in[11];
    const float* v_w    = (const float*)d_in[12];
    const float* v_b    = (const float*)d_in[13];
    float* out = (float*)d_out;

    // out layout: logits[65*513] | hidden[65*2048] | losses[65]  (fp32)
    float* outL    = out;
    float* outH    = out + (size_t)TT * LP1;
    float* outLoss = outH + (size_t)TT * DD;

    // ws layout (fp32 region, 16B-aligned slices), then bf16 W_hh region
    float* ws = (float*)d_ws;
    float* Hws      = ws;                          // 65*2048   = 133120
    float* c_buf    = Hws + (size_t)TT * DD;       // 2048
    float* enc_proj = c_buf + DD;                  // 513*2048  = 1050624
    float* xg       = enc_proj + (size_t)LP1 * DD; // 65*8192   = 532480
    float* Dm       = xg + (size_t)TT * FOURD;     // 65*2048   = 133120
    size_t base_floats = (size_t)133120 + 2048 + 1050624 + 532480 + 133120; // 1851392
    u16* Whh_b = (u16*)(ws + base_floats);         // 4*2048*2048 u16 = 33.5 MB
    size_t need = base_floats * 4 + (size_t)4 * DD * DD * 2;   // 40,960,000 B
    int use_bf16 = (ws_size >= need);

    // K-1: pack W_hh to bf16 (once per call; ws-gated)
    if (use_bf16)
        conv_whh_kernel<<<dim3(8192), 256, 0, stream>>>(W_hh, Whh_b);

    // K0: teacher-forced input-gate biases
    xg_kernel<<<dim3(32, TT), 256, 0, stream>>>(W_ih, b_ih, b_hh, seq, pos, xg);

    // K1: enc_proj = enc @ We^T + We_b   [513 x 2048]  (MFMA bf16)
    mfma_gemm_kernel<<<dim3(16, 5), 256, 0, stream>>>(enc, We_w, We_b, enc_proj,
                                                      LP1, DD, DD);

    // K2: LSTM recurrence, 65 sequential step launches
    for (int t = 0; t < TT; t++) {
        if (use_bf16)
            lstm_step_bf16_kernel<<<dim3(512), 256, 0, stream>>>(
                Whh_b, init_h, xg, Hws, c_buf, t);
        else
            lstm_step_f32_kernel<<<dim3(512), 256, 0, stream>>>(
                W_hh, init_h, xg, Hws, c_buf, t);
    }

    // K2b: hidden states to output
    copyh_kernel<<<dim3((TT * DD) / 256), 256, 0, stream>>>(Hws, outH);

    // K3: Dm = Hws @ Wd^T + Wd_b   [65 x 2048]  (MFMA bf16)
    mfma_gemm_kernel<<<dim3(16, 1), 256, 0, stream>>>(Hws, Wd_w, Wd_b, Dm,
                                                      TT, DD, DD);

    // K4: pointer logits
    ptr_kernel<<<dim3(9, 11), 256, 0, stream>>>(enc_proj, Dm, v_w, v_b, outL);

    // K5: losses
    loss_kernel<<<TT, 256, 0, stream>>>(outL, pos, outLoss);
}

// Round 8
// 704.211 us; speedup vs baseline: 1.8087x; 1.1065x over previous
//
#include <hip/hip_runtime.h>

typedef unsigned int uint32;
typedef unsigned short u16;

// Problem constants
#define DD    2048
#define LP1   513
#define TT    65
#define FOURD 8192

typedef __attribute__((ext_vector_type(8))) short short8;   // 8 bf16 (4 VGPRs)
typedef __attribute__((ext_vector_type(4))) float f32x4;

// ---------- helpers ----------
__device__ __forceinline__ float frcp(float x) { return __builtin_amdgcn_rcpf(x); }
__device__ __forceinline__ float sigm(float x) {
    return frcp(1.f + exp2f(-1.4426950408889634f * x));
}
__device__ __forceinline__ float tanh_fast(float x) {
    float e = exp2f(2.8853900817779268f * x);    // e^(2x)
    return fmaf(-2.f, frcp(1.f + e), 1.f);       // 1 - 2/(1+e^(2x))
}
__device__ __forceinline__ float bflo(uint32 w) {
    union { uint32 i; float f; } c; c.i = w << 16; return c.f;
}
__device__ __forceinline__ float bfhi(uint32 w) {
    union { uint32 i; float f; } c; c.i = w & 0xffff0000u; return c.f;
}
__device__ __forceinline__ uint32 f2bf(float f) {   // RNE, returns low 16
    union { float f; uint32 i; } c; c.f = f;
    return (c.i + 0x7fffu + ((c.i >> 16) & 1u)) >> 16;
}
__device__ __forceinline__ uint32 pack2(float a, float b) {
    return f2bf(a) | (f2bf(b) << 16);
}

// ---------- K-1: convert W_hh fp32 -> bf16 (once per call) ----------
__global__ __launch_bounds__(256) void conv_whh_kernel(
    const float* __restrict__ src, u16* __restrict__ dst)
{
    size_t i = ((size_t)blockIdx.x * 256 + threadIdx.x) * 8;   // grid covers 4*2048*2048
    float4 a = *(const float4*)(src + i);
    float4 b = *(const float4*)(src + i + 4);
    uint4 o;
    o.x = pack2(a.x, a.y); o.y = pack2(a.z, a.w);
    o.z = pack2(b.x, b.y); o.w = pack2(b.z, b.w);
    *(uint4*)(dst + i) = o;
}

// ---------- K0: xg[t][r] = b_ih[r]+b_hh[r]+W_ih[r,:]@x_t ----------
__global__ __launch_bounds__(256) void xg_kernel(
    const float* __restrict__ W_ih, const float* __restrict__ b_ih,
    const float* __restrict__ b_hh, const float* __restrict__ seq,
    const int* __restrict__ pos, float* __restrict__ xg)
{
    int t = blockIdx.y;
    int r = blockIdx.x * 256 + threadIdx.x;   // [0, 8192)
    float x0, x1, x2;
    if (t == 0) { x0 = 0.f; x1 = 0.f; x2 = 1.f; }   // special symbol
    else {
        int p = pos[t - 1];
        x0 = seq[p * 3 + 0]; x1 = seq[p * 3 + 1]; x2 = seq[p * 3 + 2];
    }
    float acc = b_ih[r] + b_hh[r];
    acc = fmaf(W_ih[r * 3 + 0], x0, acc);
    acc = fmaf(W_ih[r * 3 + 1], x1, acc);
    acc = fmaf(W_ih[r * 3 + 2], x2, acc);
    xg[(size_t)t * FOURD + r] = acc;
}

// ---------- K1/K3: MFMA GEMM  C[M,N] = A[M,K]@B[N,K]^T + bias ----------
// A,B fp32 in global, converted to bf16 at LDS-stage time. N%128==0, K%32==0.
#define LSTR 40
__global__ __launch_bounds__(256) void mfma_gemm_kernel(
    const float* __restrict__ A, const float* __restrict__ B,
    const float* __restrict__ bias, float* __restrict__ C,
    int M, int N, int K)
{
    __shared__ u16 As[128 * LSTR];
    __shared__ u16 Bs[128 * LSTR];
    int tid = threadIdx.x;
    int wave = tid >> 6, lane = tid & 63;
    int m0 = blockIdx.y * 128, n0 = blockIdx.x * 128;
    int wm = (wave >> 1) * 64, wn = (wave & 1) * 64;
    int srow = tid >> 1, sseg = (tid & 1) * 16;   // stage: row 0..127, seg 0/16

    f32x4 acc[4][4] = {};

    for (int k0 = 0; k0 < K; k0 += 32) {
        float4 a0 = {0,0,0,0}, a1 = a0, a2 = a0, a3 = a0;
        int am = m0 + srow;
        if (am < M) {
            const float4* ap = (const float4*)(A + (size_t)am * K + k0 + sseg);
            a0 = ap[0]; a1 = ap[1]; a2 = ap[2]; a3 = ap[3];
        }
        const float4* bp = (const float4*)(B + (size_t)(n0 + srow) * K + k0 + sseg);
        float4 b0 = bp[0], b1 = bp[1], b2 = bp[2], b3 = bp[3];

        __syncthreads();   // previous tile's fragment reads done
        {
            uint4 oa, ob;
            oa.x = pack2(a0.x, a0.y); oa.y = pack2(a0.z, a0.w);
            oa.z = pack2(a1.x, a1.y); oa.w = pack2(a1.z, a1.w);
            uint4* ad = (uint4*)(As + srow * LSTR + sseg);
            ad[0] = oa;
            oa.x = pack2(a2.x, a2.y); oa.y = pack2(a2.z, a2.w);
            oa.z = pack2(a3.x, a3.y); oa.w = pack2(a3.z, a3.w);
            ad[1] = oa;
            ob.x = pack2(b0.x, b0.y); ob.y = pack2(b0.z, b0.w);
            ob.z = pack2(b1.x, b1.y); ob.w = pack2(b1.z, b1.w);
            uint4* bd = (uint4*)(Bs + srow * LSTR + sseg);
            bd[0] = ob;
            ob.x = pack2(b2.x, b2.y); ob.y = pack2(b2.z, b2.w);
            ob.z = pack2(b3.x, b3.y); ob.w = pack2(b3.z, b3.w);
            bd[1] = ob;
        }
        __syncthreads();

        int fr = lane & 15, fq = (lane >> 4) * 8;
        short8 af[4], bf[4];
        #pragma unroll
        for (int i = 0; i < 4; i++)
            af[i] = *(const short8*)(As + (wm + i * 16 + fr) * LSTR + fq);
        #pragma unroll
        for (int j = 0; j < 4; j++)
            bf[j] = *(const short8*)(Bs + (wn + j * 16 + fr) * LSTR + fq);
        #pragma unroll
        for (int i = 0; i < 4; i++)
            #pragma unroll
            for (int j = 0; j < 4; j++)
                acc[i][j] = __builtin_amdgcn_mfma_f32_16x16x32_bf16(
                    af[i], bf[j], acc[i][j], 0, 0, 0);
    }

    // epilogue: C/D layout col=lane&15, row=(lane>>4)*4+reg  [m89-verified]
    int cn = lane & 15, cr = (lane >> 4) * 4;
    #pragma unroll
    for (int i = 0; i < 4; i++) {
        #pragma unroll
        for (int r = 0; r < 4; r++) {
            int m = m0 + wm + i * 16 + cr + r;
            if (m < M) {
                #pragma unroll
                for (int j = 0; j < 4; j++) {
                    int n = n0 + wn + j * 16 + cn;
                    C[(size_t)m * N + n] = acc[i][j][r] + bias[n];
                }
            }
        }
    }
}

// ---------- K2 (x65): one LSTM step, W_hh in bf16 ----------
__global__ __launch_bounds__(256) void lstm_step_bf16_kernel(
    const u16* __restrict__ Wb, const float* __restrict__ init_h,
    const float* __restrict__ xg, float* __restrict__ Hws,
    float* __restrict__ c_buf, int t)
{
    __shared__ float4 h_s4[512];   // 8 KB: h_{t-1}
    int tid = threadIdx.x;
    int b = blockIdx.x;
    int wave = tid >> 6, lane = tid & 63;
    int d = b * 4 + wave;

    {
        const float4* src = (t == 0) ? (const float4*)init_h
                                     : (const float4*)(Hws + (size_t)(t - 1) * DD);
        h_s4[tid] = src[tid];
        h_s4[tid + 256] = src[tid + 256];
    }
    __syncthreads();

    const uint4* Wq = (const uint4*)Wb;   // row r: 256 uint4 (2048 bf16)
    float s0 = 0.f, s1 = 0.f, s2 = 0.f, s3 = 0.f;
    #pragma unroll
    for (int i = 0; i < 4; i++) {
        int p = i * 64 + lane;            // uint4 index 0..255 → k = 8p..8p+7
        float4 ha = h_s4[2 * p], hb = h_s4[2 * p + 1];
        uint4 w0 = Wq[(size_t)(0 * DD + d) * 256 + p];
        uint4 w1 = Wq[(size_t)(1 * DD + d) * 256 + p];
        uint4 w2 = Wq[(size_t)(2 * DD + d) * 256 + p];
        uint4 w3 = Wq[(size_t)(3 * DD + d) * 256 + p];
        s0 = fmaf(bflo(w0.x), ha.x, s0); s0 = fmaf(bfhi(w0.x), ha.y, s0);
        s0 = fmaf(bflo(w0.y), ha.z, s0); s0 = fmaf(bfhi(w0.y), ha.w, s0);
        s0 = fmaf(bflo(w0.z), hb.x, s0); s0 = fmaf(bfhi(w0.z), hb.y, s0);
        s0 = fmaf(bflo(w0.w), hb.z, s0); s0 = fmaf(bfhi(w0.w), hb.w, s0);
        s1 = fmaf(bflo(w1.x), ha.x, s1); s1 = fmaf(bfhi(w1.x), ha.y, s1);
        s1 = fmaf(bflo(w1.y), ha.z, s1); s1 = fmaf(bfhi(w1.y), ha.w, s1);
        s1 = fmaf(bflo(w1.z), hb.x, s1); s1 = fmaf(bfhi(w1.z), hb.y, s1);
        s1 = fmaf(bflo(w1.w), hb.z, s1); s1 = fmaf(bfhi(w1.w), hb.w, s1);
        s2 = fmaf(bflo(w2.x), ha.x, s2); s2 = fmaf(bfhi(w2.x), ha.y, s2);
        s2 = fmaf(bflo(w2.y), ha.z, s2); s2 = fmaf(bfhi(w2.y), ha.w, s2);
        s2 = fmaf(bflo(w2.z), hb.x, s2); s2 = fmaf(bfhi(w2.z), hb.y, s2);
        s2 = fmaf(bflo(w2.w), hb.z, s2); s2 = fmaf(bfhi(w2.w), hb.w, s2);
        s3 = fmaf(bflo(w3.x), ha.x, s3); s3 = fmaf(bfhi(w3.x), ha.y, s3);
        s3 = fmaf(bflo(w3.y), ha.z, s3); s3 = fmaf(bfhi(w3.y), ha.w, s3);
        s3 = fmaf(bflo(w3.z), hb.x, s3); s3 = fmaf(bfhi(w3.z), hb.y, s3);
        s3 = fmaf(bflo(w3.w), hb.z, s3); s3 = fmaf(bfhi(w3.w), hb.w, s3);
    }
    #pragma unroll
    for (int off = 1; off < 64; off <<= 1) {
        s0 += __shfl_xor(s0, off); s1 += __shfl_xor(s1, off);
        s2 += __shfl_xor(s2, off); s3 += __shfl_xor(s3, off);
    }
    const float* xgt = xg + (size_t)t * FOURD;
    s0 += xgt[d]; s1 += xgt[DD + d]; s2 += xgt[2 * DD + d]; s3 += xgt[3 * DD + d];

    float cprev = (t == 0) ? 0.f : c_buf[d];
    float ig = sigm(s0), fg = sigm(s1), gg = tanh_fast(s2), og = sigm(s3);
    float c = fmaf(fg, cprev, ig * gg);
    float hh = og * tanh_fast(c);
    if (lane == 0) {
        c_buf[d] = c;
        Hws[(size_t)t * DD + d] = hh;
    }
}

// ---------- K2-fallback: fp32 step (used if ws too small for bf16 W) ----------
__global__ __launch_bounds__(256) void lstm_step_f32_kernel(
    const float* __restrict__ Whh, const float* __restrict__ init_h,
    const float* __restrict__ xg, float* __restrict__ Hws,
    float* __restrict__ c_buf, int t)
{
    __shared__ float4 h_s4[512];
    int tid = threadIdx.x;
    int b = blockIdx.x;
    int wave = tid >> 6, lane = tid & 63;
    int d = b * 4 + wave;
    {
        const float4* src = (t == 0) ? (const float4*)init_h
                                     : (const float4*)(Hws + (size_t)(t - 1) * DD);
        h_s4[tid] = src[tid];
        h_s4[tid + 256] = src[tid + 256];
    }
    __syncthreads();
    const float4* Wq = (const float4*)Whh;
    float s0 = 0.f, s1 = 0.f, s2 = 0.f, s3 = 0.f;
    #pragma unroll
    for (int i = 0; i < 8; i++) {
        int p = i * 64 + lane;
        float4 h = h_s4[p];
        float4 w0 = Wq[(size_t)(0 * DD + d) * 512 + p];
        float4 w1 = Wq[(size_t)(1 * DD + d) * 512 + p];
        float4 w2 = Wq[(size_t)(2 * DD + d) * 512 + p];
        float4 w3 = Wq[(size_t)(3 * DD + d) * 512 + p];
        s0 = fmaf(w0.x, h.x, s0); s0 = fmaf(w0.y, h.y, s0);
        s0 = fmaf(w0.z, h.z, s0); s0 = fmaf(w0.w, h.w, s0);
        s1 = fmaf(w1.x, h.x, s1); s1 = fmaf(w1.y, h.y, s1);
        s1 = fmaf(w1.z, h.z, s1); s1 = fmaf(w1.w, h.w, s1);
        s2 = fmaf(w2.x, h.x, s2); s2 = fmaf(w2.y, h.y, s2);
        s2 = fmaf(w2.z, h.z, s2); s2 = fmaf(w2.w, h.w, s2);
        s3 = fmaf(w3.x, h.x, s3); s3 = fmaf(w3.y, h.y, s3);
        s3 = fmaf(w3.z, h.z, s3); s3 = fmaf(w3.w, h.w, s3);
    }
    #pragma unroll
    for (int off = 1; off < 64; off <<= 1) {
        s0 += __shfl_xor(s0, off); s1 += __shfl_xor(s1, off);
        s2 += __shfl_xor(s2, off); s3 += __shfl_xor(s3, off);
    }
    const float* xgt = xg + (size_t)t * FOURD;
    s0 += xgt[d]; s1 += xgt[DD + d]; s2 += xgt[2 * DD + d]; s3 += xgt[3 * DD + d];
    float cprev = (t == 0) ? 0.f : c_buf[d];
    float ig = sigm(s0), fg = sigm(s1), gg = tanh_fast(s2), og = sigm(s3);
    float c = fmaf(fg, cprev, ig * gg);
    float hh = og * tanh_fast(c);
    if (lane == 0) {
        c_buf[d] = c;
        Hws[(size_t)t * DD + d] = hh;
    }
}

// ---------- K2b: copy Hws -> d_out hidden slice ----------
__global__ __launch_bounds__(256) void copyh_kernel(
    const float* __restrict__ Hws, float* __restrict__ outH)
{
    int i = blockIdx.x * 256 + threadIdx.x;
    outH[i] = Hws[i];
}

// ---------- K4: logits[t][l] = v_b + sum_v vw[v]*tanh(enc_proj[l][v]+Dm[t][v]) ----------
// One t per block: grid (9 l-tiles, 65 t) = 585 blocks, 16 KB LDS.
// (R7 profile: 99-block version was parallelism-starved — Occupancy 3.7%.)
__global__ __launch_bounds__(256) void ptr_kernel(
    const float* __restrict__ enc_proj, const float* __restrict__ Dm,
    const float* __restrict__ vw, const float* __restrict__ vb,
    float* __restrict__ outL)
{
    __shared__ float Dm_s[DD];   // 8 KB
    __shared__ float vw_s[DD];   // 8 KB
    int tid = threadIdx.x;
    int t = blockIdx.y;          // 0..64
    int l0 = blockIdx.x * 64;

    {   // stage Dm[t] and vw: 512 float4 each, 256 threads x 2
        const float4* sd = (const float4*)(Dm + (size_t)t * DD);
        ((float4*)Dm_s)[tid] = sd[tid];
        ((float4*)Dm_s)[tid + 256] = sd[tid + 256];
        const float4* sv = (const float4*)vw;
        ((float4*)vw_s)[tid] = sv[tid];
        ((float4*)vw_s)[tid + 256] = sv[tid + 256];
    }
    __syncthreads();

    int wave = tid >> 6, lane = tid & 63;
    float vbf = vb[0];

    for (int lo = wave; lo < 64; lo += 4) {
        int l = l0 + lo;
        if (l >= LP1) break;
        const float* ep = enc_proj + (size_t)l * DD;
        float acc = 0.f;
        #pragma unroll 8
        for (int i2 = 0; i2 < 32; i2++) {
            int v = lane + (i2 << 6);
            acc = fmaf(vw_s[v], tanh_fast(ep[v] + Dm_s[v]), acc);
        }
        #pragma unroll
        for (int off = 1; off < 64; off <<= 1)
            acc += __shfl_xor(acc, off);
        if (lane == 0)
            outL[(size_t)t * LP1 + l] = acc + vbf;
    }
}

// ---------- K5: losses[t] = logsumexp(logits[t]) - logits[t][tgt] ----------
__global__ __launch_bounds__(256) void loss_kernel(
    const float* __restrict__ LG, const int* __restrict__ pos,
    float* __restrict__ outLoss)
{
    int t = blockIdx.x, tid = threadIdx.x;
    __shared__ float red[256];
    const float* row = LG + (size_t)t * LP1;

    float m = -3.4e38f;
    for (int i = tid; i < LP1; i += 256) m = fmaxf(m, row[i]);
    red[tid] = m; __syncthreads();
    for (int s = 128; s > 0; s >>= 1) {
        if (tid < s) red[tid] = fmaxf(red[tid], red[tid + s]);
        __syncthreads();
    }
    float mx = red[0]; __syncthreads();

    float sum = 0.f;
    for (int i = tid; i < LP1; i += 256)
        sum += exp2f((row[i] - mx) * 1.4426950408889634f);
    red[tid] = sum; __syncthreads();
    for (int s = 128; s > 0; s >>= 1) {
        if (tid < s) red[tid] += red[tid + s];
        __syncthreads();
    }
    if (tid == 0) {
        int tgt = (t < TT - 1) ? pos[t] : (LP1 - 1);
        float lse = mx + 0.6931471805599453f * log2f(red[0]);
        outLoss[t] = lse - row[tgt];
    }
}

// ---------- host ----------
extern "C" void kernel_launch(void* const* d_in, const int* in_sizes, int n_in,
                              void* d_out, int out_size, void* d_ws, size_t ws_size,
                              hipStream_t stream) {
    const float* init_h = (const float*)d_in[0];
    const float* enc    = (const float*)d_in[1];
    const float* seq    = (const float*)d_in[2];
    const int*   pos    = (const int*)d_in[3];
    const float* W_ih   = (const float*)d_in[4];
    const float* W_hh   = (const float*)d_in[5];
    const float* b_ih   = (const float*)d_in[6];
    const float* b_hh   = (const float*)d_in[7];
    const float* We_w   = (const float*)d_in[8];
    const float* We_b   = (const float*)d_in[9];
    const float* Wd_w   = (const float*)d_in[10];
    const float* Wd_b   = (const float*)d_in[11];
    const float* v_w    = (const float*)d_in[12];
    const float* v_b    = (const float*)d_in[13];
    float* out = (float*)d_out;

    // out layout: logits[65*513] | hidden[65*2048] | losses[65]  (fp32)
    float* outL    = out;
    float* outH    = out + (size_t)TT * LP1;
    float* outLoss = outH + (size_t)TT * DD;

    // ws layout (fp32 region, 16B-aligned slices), then bf16 W_hh region
    float* ws = (float*)d_ws;
    float* Hws      = ws;                          // 65*2048   = 133120
    float* c_buf    = Hws + (size_t)TT * DD;       // 2048
    float* enc_proj = c_buf + DD;                  // 513*2048  = 1050624
    float* xg       = enc_proj + (size_t)LP1 * DD; // 65*8192   = 532480
    float* Dm       = xg + (size_t)TT * FOURD;     // 65*2048   = 133120
    size_t base_floats = (size_t)133120 + 2048 + 1050624 + 532480 + 133120; // 1851392
    u16* Whh_b = (u16*)(ws + base_floats);         // 4*2048*2048 u16 = 33.5 MB
    size_t need = base_floats * 4 + (size_t)4 * DD * DD * 2;   // ~41 MB
    int use_bf16 = (ws_size >= need);

    // K-1: pack W_hh to bf16 (once per call; ws-gated)
    if (use_bf16)
        conv_whh_kernel<<<dim3(8192), 256, 0, stream>>>(W_hh, Whh_b);

    // K0: teacher-forced input-gate biases
    xg_kernel<<<dim3(32, TT), 256, 0, stream>>>(W_ih, b_ih, b_hh, seq, pos, xg);

    // K1: enc_proj = enc @ We^T + We_b   [513 x 2048]  (MFMA bf16)
    mfma_gemm_kernel<<<dim3(16, 5), 256, 0, stream>>>(enc, We_w, We_b, enc_proj,
                                                      LP1, DD, DD);

    // K2: LSTM recurrence, 65 sequential step launches
    for (int t = 0; t < TT; t++) {
        if (use_bf16)
            lstm_step_bf16_kernel<<<dim3(512), 256, 0, stream>>>(
                Whh_b, init_h, xg, Hws, c_buf, t);
        else
            lstm_step_f32_kernel<<<dim3(512), 256, 0, stream>>>(
                W_hh, init_h, xg, Hws, c_buf, t);
    }

    // K2b: hidden states to output
    copyh_kernel<<<dim3((TT * DD) / 256), 256, 0, stream>>>(Hws, outH);

    // K3: Dm = Hws @ Wd^T + Wd_b   [65 x 2048]  (MFMA bf16)
    mfma_gemm_kernel<<<dim3(16, 1), 256, 0, stream>>>(Hws, Wd_w, Wd_b, Dm,
                                                      TT, DD, DD);

    // K4: pointer logits (585 blocks: one t per block)
    ptr_kernel<<<dim3(9, TT), 256, 0, stream>>>(enc_proj, Dm, v_w, v_b, outL);

    // K5: losses
    loss_kernel<<<TT, 256, 0, stream>>>(outL, pos, outLoss);
}